// Round 3
// baseline (246.573 us; speedup 1.0000x reference)
//
#include <hip/hip_runtime.h>
#include <math.h>

// Problem constants
#define BB   8
#define SS   100
#define TT   1200        // S * DMAX
#define NM   80          // NMEL
#define DMC  128         // DM
#define KK   9
#define G3   384         // 3*DM
#define NROW (BB*TT)     // 9600

typedef __attribute__((ext_vector_type(8))) short short8;
typedef __attribute__((ext_vector_type(4))) float f32x4;

__device__ __forceinline__ float sigmoid_(float v) { return 1.f / (1.f + __expf(-v)); }
__device__ __forceinline__ float tanh_(float v) {
    float a = fabsf(v);
    float e = __expf(-2.f * a);
    float t = (1.f - e) / (1.f + e);
    return copysignf(t, v);
}
__device__ __forceinline__ unsigned short f2bf(float f) {   // RNE fp32->bf16
    unsigned int u = __float_as_uint(f);
    unsigned int r = (u + 0x7fffu + ((u >> 16) & 1u)) >> 16;
    return (unsigned short)r;
}

// ---------------------------------------------------------------------------
// Kernel S: per-batch prefix sum of durations -> starts[b][s]
// ---------------------------------------------------------------------------
__global__ void k_starts(const int* __restrict__ dur, int* __restrict__ starts) {
    __shared__ int buf[BB][128];
    int s = threadIdx.x;   // 0..127
    int b = threadIdx.y;   // 0..7
    int v = (s < SS) ? dur[b * SS + s] : 0;
    buf[b][s] = v;
    __syncthreads();
    for (int off = 1; off < 128; off <<= 1) {
        int t = (s >= off) ? buf[b][s - off] : 0;
        __syncthreads();
        buf[b][s] += t;
        __syncthreads();
    }
    if (s < SS) starts[b * SS + s] = buf[b][s] - v;  // exclusive scan
}

// ---------------------------------------------------------------------------
// Kernel W: pack w_hh into MFMA A-fragment order, split bf16 (hi + lo).
// A-frag (16x16x32 bf16): lane holds A[m=lane&15][k=(lane>>4)*8 + j], j=0..7
// index = (((dir*24+tau)*4+k32)*64 + lane)*8 + j
// ---------------------------------------------------------------------------
__global__ void k_wpack(const float* __restrict__ wf, const float* __restrict__ wb,
                        unsigned short* __restrict__ wph, unsigned short* __restrict__ wpl) {
    int idx = blockIdx.x * 256 + threadIdx.x;    // over 2*24*4*64 = 12288
    if (idx >= 2 * 24 * 4 * 64) return;
    int lane = idx & 63;
    int k32  = (idx >> 6) & 3;
    int tau  = (idx >> 8) % 24;
    int dir  = idx / (24 * 4 * 64);
    const float* w = dir ? wb : wf;
    int g = tau * 16 + (lane & 15);
    int kbase = k32 * 32 + (lane >> 4) * 8;
#pragma unroll
    for (int j = 0; j < 8; j++) {
        float v = w[g * DMC + kbase + j];
        unsigned short hi = f2bf(v);
        float hif = __uint_as_float(((unsigned)hi) << 16);
        unsigned short lo = f2bf(v - hif);
        wph[idx * 8 + j] = hi;
        wpl[idx * 8 + j] = lo;
    }
}

// ---------------------------------------------------------------------------
// Kernel A: fused conv1 + BN/ReLU + conv2 + BN/ReLU, one (b,t) row per block.
// y1 layout [d][90]: stride 90 dw == 26 mod 32, gcd 2 -> <=2-way LDS (free).
// conv2: thread=(dp of 24, mg of 10), 8-m blocks -> 72 FMA per 4 ds_read_b128.
// LDS total 54,096 B -> 3 wg/CU.
// ---------------------------------------------------------------------------
__global__ __launch_bounds__(256) void k_conv(
    const float* __restrict__ mel, const int* __restrict__ mel_len,
    const float* __restrict__ w1, const float* __restrict__ g1, const float* __restrict__ be1,
    const float* __restrict__ w2, const float* __restrict__ g2, const float* __restrict__ be2,
    float* __restrict__ xout) {
    int t = blockIdx.x, b = blockIdx.y;
    if (t >= mel_len[b]) return;   // row never consumed downstream

    __shared__ __align__(16) float melp[88];         // melp[i] = mel[i-4], i in [0,88)
    __shared__ __align__(16) float y1[DMC][90];      // y1[d][m''], m'' in [0,88), pad->90
    __shared__ __align__(16) float part[24][80];     // conv2 partials

    int tid = threadIdx.x;
    const float inv_sqrt = 0.9999950000374997f;      // 1/sqrt(1+1e-5)

    if (tid < 88) {
        float v = 0.f;
        if (tid >= 4 && tid < 84) v = mel[(b * TT + t) * NM + tid - 4];
        melp[tid] = v;
    }
    __syncthreads();

    // ---- conv1: thread = (d, half-row of 40 m); BN1 scale folded into w ----
    {
        int d = tid >> 1, h = tid & 1, ms = h * 40;
        float sc = g1[d] * inv_sqrt;
        float wr[KK];
#pragma unroll
        for (int k = 0; k < KK; k++) wr[k] = w1[d * KK + k] * sc;
        float sb = be1[d];
        float win[48];
        const float4* mp4 = (const float4*)(melp + ms);
#pragma unroll
        for (int q = 0; q < 12; q++) {
            float4 v = mp4[q];
            win[q*4+0] = v.x; win[q*4+1] = v.y; win[q*4+2] = v.z; win[q*4+3] = v.w;
        }
        if (h == 0) { *(float2*)&y1[d][0] = make_float2(0.f, 0.f);
                      *(float2*)&y1[d][2] = make_float2(0.f, 0.f); }
        else        { *(float2*)&y1[d][84] = make_float2(0.f, 0.f);
                      *(float2*)&y1[d][86] = make_float2(0.f, 0.f); }
#pragma unroll
        for (int m = 0; m < 40; m += 2) {
            float a0 = 0.f, a1 = 0.f;
#pragma unroll
            for (int k = 0; k < KK; k++) {
                a0 = fmaf(wr[k], win[m + k], a0);
                a1 = fmaf(wr[k], win[m + 1 + k], a1);
            }
            a0 = fmaxf(0.f, a0 + sb);
            a1 = fmaxf(0.f, a1 + sb);
            *(float2*)&y1[d][4 + ms + m] = make_float2(a0, a1);   // 8B-aligned, 2-way max
        }
    }
    __syncthreads();

    // ---- conv2 partials: thread = (dp of 24, mg of 10 blocks of 8 m) ----
    if (tid < 240) {
        int dp = tid / 10, mg = tid - dp * 10;     // dp-major: wave spans dp 0..6
        float acc[8];
#pragma unroll
        for (int mm = 0; mm < 8; mm++) acc[mm] = 0.f;
        int nd = (dp < 8) ? 6 : 5;                 // 8*6 + 16*5 = 128
        for (int i = 0; i < nd; i++) {
            int d = dp + 24 * i;
            const float4* yr = (const float4*)&y1[d][mg * 8];   // 32B-aligned
            float4 qa = yr[0], qb = yr[1], qc = yr[2], qd = yr[3];
            float w16[16] = {qa.x,qa.y,qa.z,qa.w, qb.x,qb.y,qb.z,qb.w,
                             qc.x,qc.y,qc.z,qc.w, qd.x,qd.y,qd.z,qd.w};
            const float* w2d = w2 + d * KK;
            float wv[KK];
#pragma unroll
            for (int k = 0; k < KK; k++) wv[k] = w2d[k];
#pragma unroll
            for (int mm = 0; mm < 8; mm++) {
#pragma unroll
                for (int k = 0; k < KK; k++)
                    acc[mm] = fmaf(wv[k], w16[mm + k], acc[mm]);
            }
        }
#pragma unroll
        for (int mm = 0; mm < 8; mm += 2)
            *(float2*)&part[dp][mg * 8 + mm] = make_float2(acc[mm], acc[mm + 1]);
    }
    __syncthreads();

    // ---- reduce partials + BN2/ReLU + store ----
    if (tid < NM) {
        float s = 0.f;
#pragma unroll
        for (int dp = 0; dp < 24; dp++) s += part[dp][tid];
        float v = fmaxf(0.f, fmaf(s, g2[0] * inv_sqrt, be2[0]));
        xout[(b * TT + t) * NM + tid] = v;
    }
}

// ---------------------------------------------------------------------------
// Kernel B: projection GEMM  xall[row][0:384]=f-gates, [384:768]=b-gates
// ---------------------------------------------------------------------------
__global__ __launch_bounds__(256) void k_proj(
    const float* __restrict__ x,
    const float* __restrict__ wf, const float* __restrict__ wb,
    const float* __restrict__ bf, const float* __restrict__ bbv,
    float* __restrict__ xall) {
    __shared__ __align__(16) float xs[32 * 84];
    __shared__ __align__(16) float wsh[96 * 84];

    int tid = threadIdx.x;
    int row0 = blockIdx.x * 32;
    int cb = blockIdx.y;           // 0..7 ; 0..3 fwd, 4..7 bwd
    int g0 = cb * 96;              // global col
    const float* w    = (cb < 4) ? (wf + g0 * NM) : (wb + (g0 - G3) * NM);
    const float* bias = (cb < 4) ? (bf + g0)      : (bbv + (g0 - G3));

    for (int i = tid; i < 32 * NM; i += 256) {
        int r = i / NM, c = i - r * NM;
        xs[r * 84 + c] = x[(row0 + r) * NM + c];
    }
    for (int i = tid; i < 96 * NM; i += 256) {
        int r = i / NM, c = i - r * NM;
        wsh[r * 84 + c] = w[i];
    }
    __syncthreads();

    int cp = tid & 15, rp = tid >> 4;
    float4 acc[2][6];
#pragma unroll
    for (int rr = 0; rr < 2; rr++)
#pragma unroll
        for (int j = 0; j < 6; j++) acc[rr][j] = make_float4(0.f, 0.f, 0.f, 0.f);

    const float4* xs4 = (const float4*)xs;
    const float4* ws4 = (const float4*)wsh;
#pragma unroll
    for (int kc = 0; kc < 20; kc++) {
        float4 xa = xs4[rp * 21 + kc];
        float4 xbv = xs4[(rp + 16) * 21 + kc];
#pragma unroll
        for (int j = 0; j < 6; j++) {
            float4 wv = ws4[(cp + 16 * j) * 21 + kc];
            acc[0][j].x = fmaf(xa.x, wv.x, acc[0][j].x);
            acc[0][j].y = fmaf(xa.y, wv.y, acc[0][j].y);
            acc[0][j].z = fmaf(xa.z, wv.z, acc[0][j].z);
            acc[0][j].w = fmaf(xa.w, wv.w, acc[0][j].w);
            acc[1][j].x = fmaf(xbv.x, wv.x, acc[1][j].x);
            acc[1][j].y = fmaf(xbv.y, wv.y, acc[1][j].y);
            acc[1][j].z = fmaf(xbv.z, wv.z, acc[1][j].z);
            acc[1][j].w = fmaf(xbv.w, wv.w, acc[1][j].w);
        }
    }
#pragma unroll
    for (int rr = 0; rr < 2; rr++)
#pragma unroll
        for (int j = 0; j < 6; j++) {
            float4 a = acc[rr][j];
            float v = a.x + a.y + a.z + a.w + bias[cp + 16 * j];
            int row = row0 + rp + 16 * rr;
            xall[row * 768 + g0 + cp + 16 * j] = v;
        }
}

// ---------------------------------------------------------------------------
// Kernel C: per-segment GRU via MFMA, split-bf16 for fp32-class accuracy.
// grid (7 s-blocks of 16 segs, 8 b, 2 dir), 384 threads (6 waves).
// ---------------------------------------------------------------------------
__global__ __launch_bounds__(384) void k_gru(
    const float* __restrict__ xall,
    const unsigned short* __restrict__ wph, const unsigned short* __restrict__ wpl,
    const int* __restrict__ dur_all, const int* __restrict__ starts,
    const int* __restrict__ src_len,
    const float* __restrict__ bhf, const float* __restrict__ bhb,
    float* __restrict__ out) {
    int sblk = blockIdx.x;   // 0..6
    int b    = blockIdx.y;   // 0..7
    int dir  = blockIdx.z;   // 0 fwd, 1 bwd
    int s0 = sblk * 16;

    __shared__ __align__(16) float hs[16][DMC];                 // fp32 h (exact)
    __shared__ __align__(16) unsigned short hbh[4 * 64 * 8];    // B-frag layout, hi
    __shared__ __align__(16) unsigned short hbl[4 * 64 * 8];    // B-frag layout, lo
    __shared__ __align__(16) float gbuf[16][388];               // gates [seg][g]
    __shared__ int sdur[16], sstart[16];

    int tid  = threadIdx.x;
    int wave = tid >> 6, lane = tid & 63;

    if (tid < 16) {
        int s = s0 + tid;
        sdur[tid]   = (s < SS) ? dur_all[b * SS + s] : 0;
        sstart[tid] = (s < SS) ? starts[b * SS + s]  : 0;
    }
    for (int i = tid; i < 16 * DMC; i += 384) ((float*)hs)[i] = 0.f;
    for (int i = tid; i < 2048; i += 384) { hbh[i] = 0; hbl[i] = 0; }

    // ---- load A-fragments once (registers, persist all 12 iterations) ----
    short8 Ah[4][4], Al[4][4];
    const short8* wph8 = (const short8*)wph;
    const short8* wpl8 = (const short8*)wpl;
#pragma unroll
    for (int tt = 0; tt < 4; tt++)
#pragma unroll
        for (int k32 = 0; k32 < 4; k32++) {
            int tau = wave * 4 + tt;
            int idx = ((dir * 24 + tau) * 4 + k32) * 64 + lane;
            Ah[tt][k32] = wph8[idx];
            Al[tt][k32] = wpl8[idx];
        }

    const float* bh = dir ? bhb : bhf;
    int xbase = dir * G3;
    int seg_c = lane & 15, quad = lane >> 4;
    __syncthreads();

    for (int i = 0; i < 12; i++) {
        // ---- phase 1: D[g][seg] = h . w_hh   (3-term split-bf16 MFMA) ----
        f32x4 acc[4];
#pragma unroll
        for (int tt = 0; tt < 4; tt++) acc[tt] = (f32x4){0.f, 0.f, 0.f, 0.f};
#pragma unroll
        for (int k32 = 0; k32 < 4; k32++) {
            short8 Bh = ((const short8*)hbh)[k32 * 64 + lane];
            short8 Bl = ((const short8*)hbl)[k32 * 64 + lane];
#pragma unroll
            for (int tt = 0; tt < 4; tt++) {
                acc[tt] = __builtin_amdgcn_mfma_f32_16x16x32_bf16(Ah[tt][k32], Bh, acc[tt], 0, 0, 0);
                acc[tt] = __builtin_amdgcn_mfma_f32_16x16x32_bf16(Ah[tt][k32], Bl, acc[tt], 0, 0, 0);
                acc[tt] = __builtin_amdgcn_mfma_f32_16x16x32_bf16(Al[tt][k32], Bh, acc[tt], 0, 0, 0);
            }
        }
#pragma unroll
        for (int tt = 0; tt < 4; tt++) {
            int g = (wave * 4 + tt) * 16 + quad * 4;    // row = quad*4+reg (m89)
            *(f32x4*)&gbuf[seg_c][g] = acc[tt];
        }
        __syncthreads();

        // ---- phase 2: elementwise GRU update + output gather ----
        for (int u = tid; u < 16 * DMC; u += 384) {
            int seg = u >> 7, j = u & 127;
            int d = sdur[seg];
            if (i < d) {
                int t = dir ? (sstart[seg] + d - 1 - i) : (sstart[seg] + i);
                const float* xrow = xall + (b * TT + t) * 768 + xbase;
                float xr = xrow[j], xz = xrow[DMC + j], xn = xrow[2 * DMC + j];
                float hr = gbuf[seg][j]           + bh[j];
                float hz = gbuf[seg][DMC + j]     + bh[DMC + j];
                float hn = gbuf[seg][2 * DMC + j] + bh[2 * DMC + j];
                float hold = hs[seg][j];
                float r = sigmoid_(xr + hr);
                float z = sigmoid_(xz + hz);
                float n = tanh_(xn + r * hn);
                float hnew = (1.f - z) * n + z * hold;
                hs[seg][j] = hnew;
                // split-bf16 copies in B-frag layout: k = j
                unsigned short hi = f2bf(hnew);
                float hif = __uint_as_float(((unsigned)hi) << 16);
                unsigned short lo = f2bf(hnew - hif);
                int addr = ((j >> 5) * 64 + ((j & 31) >> 3) * 16 + seg) * 8 + (j & 7);
                hbh[addr] = hi;
                hbl[addr] = lo;
                if (i == d - 1) {
                    int s = s0 + seg;
                    float vout = (s < src_len[b]) ? hnew : 0.f;
                    out[(b * SS + s) * (2 * DMC) + dir * DMC + j] = vout;
                }
            }
        }
        __syncthreads();
    }
}

// ---------------------------------------------------------------------------
extern "C" void kernel_launch(void* const* d_in, const int* in_sizes, int n_in,
                              void* d_out, int out_size, void* d_ws, size_t ws_size,
                              hipStream_t stream) {
    const float* mel      = (const float*)d_in[0];
    const int*   durations= (const int*)  d_in[1];
    const int*   mel_len  = (const int*)  d_in[2];
    const int*   src_len  = (const int*)  d_in[3];
    const float* w1       = (const float*)d_in[4];
    const float* g1       = (const float*)d_in[5];
    const float* be1      = (const float*)d_in[6];
    const float* w2       = (const float*)d_in[7];
    const float* g2       = (const float*)d_in[8];
    const float* be2      = (const float*)d_in[9];
    const float* w_ih_f   = (const float*)d_in[10];
    const float* w_hh_f   = (const float*)d_in[11];
    const float* b_ih_f   = (const float*)d_in[12];
    const float* b_hh_f   = (const float*)d_in[13];
    const float* w_ih_b   = (const float*)d_in[14];
    const float* w_hh_b   = (const float*)d_in[15];
    const float* b_ih_b   = (const float*)d_in[16];
    const float* b_hh_b   = (const float*)d_in[17];
    float* out = (float*)d_out;

    // workspace layout: x[9600*80] f | xall[9600*768] f | wph/wpl[2*24*4*64*8] u16 | starts[800] i32
    float* x     = (float*)d_ws;
    float* xall  = x + NROW * NM;
    unsigned short* wph = (unsigned short*)(xall + NROW * 768);
    unsigned short* wpl = wph + 2 * 24 * 4 * 64 * 8;
    int*   starts= (int*)(wpl + 2 * 24 * 4 * 64 * 8);

    k_starts<<<1, dim3(128, 8), 0, stream>>>(durations, starts);
    k_wpack<<<48, 256, 0, stream>>>(w_hh_f, w_hh_b, wph, wpl);
    k_conv<<<dim3(TT, BB), 256, 0, stream>>>(mel, mel_len, w1, g1, be1, w2, g2, be2, x);
    k_proj<<<dim3(NROW / 32, 8), 256, 0, stream>>>(x, w_ih_f, w_ih_b, b_ih_f, b_ih_b, xall);
    k_gru<<<dim3(7, 8, 2), 384, 0, stream>>>(xall, wph, wpl, durations, starts, src_len,
                                             b_hh_f, b_hh_b, out);
}

// Round 4
// 206.336 us; speedup vs baseline: 1.1950x; 1.1950x over previous
//
#include <hip/hip_runtime.h>
#include <math.h>

// Problem constants
#define BB   8
#define SS   100
#define TT   1200        // S * DMAX
#define NM   80          // NMEL
#define DMC  128         // DM
#define KK   9
#define G3   384         // 3*DM
#define NROW (BB*TT)     // 9600

typedef __attribute__((ext_vector_type(8))) short short8;
typedef __attribute__((ext_vector_type(4))) float f32x4;

__device__ __forceinline__ float sigmoid_(float v) { return 1.f / (1.f + __expf(-v)); }
__device__ __forceinline__ float tanh_(float v) {
    float a = fabsf(v);
    float e = __expf(-2.f * a);
    float t = (1.f - e) / (1.f + e);
    return copysignf(t, v);
}
__device__ __forceinline__ unsigned short f2bf(float f) {   // RNE fp32->bf16
    unsigned int u = __float_as_uint(f);
    unsigned int r = (u + 0x7fffu + ((u >> 16) & 1u)) >> 16;
    return (unsigned short)r;
}

// ---------------------------------------------------------------------------
// Kernel S: per-batch prefix sum of durations -> starts[b][s]
// ---------------------------------------------------------------------------
__global__ void k_starts(const int* __restrict__ dur, int* __restrict__ starts) {
    __shared__ int buf[BB][128];
    int s = threadIdx.x;   // 0..127
    int b = threadIdx.y;   // 0..7
    int v = (s < SS) ? dur[b * SS + s] : 0;
    buf[b][s] = v;
    __syncthreads();
    for (int off = 1; off < 128; off <<= 1) {
        int t = (s >= off) ? buf[b][s - off] : 0;
        __syncthreads();
        buf[b][s] += t;
        __syncthreads();
    }
    if (s < SS) starts[b * SS + s] = buf[b][s] - v;  // exclusive scan
}

// ---------------------------------------------------------------------------
// Kernel W1: pack w_hh into MFMA A-fragment order, split bf16 (hi + lo).
// A-frag (16x16x32 bf16): lane holds A[m=lane&15][k=(lane>>4)*8 + j], j=0..7
// ---------------------------------------------------------------------------
__global__ void k_wpack(const float* __restrict__ wf, const float* __restrict__ wb,
                        unsigned short* __restrict__ wph, unsigned short* __restrict__ wpl) {
    int idx = blockIdx.x * 256 + threadIdx.x;    // over 2*24*4*64 = 12288
    if (idx >= 2 * 24 * 4 * 64) return;
    int lane = idx & 63;
    int k32  = (idx >> 6) & 3;
    int tau  = (idx >> 8) % 24;
    int dir  = idx / (24 * 4 * 64);
    const float* w = dir ? wb : wf;
    int g = tau * 16 + (lane & 15);
    int kbase = k32 * 32 + (lane >> 4) * 8;
#pragma unroll
    for (int j = 0; j < 8; j++) {
        float v = w[g * DMC + kbase + j];
        unsigned short hi = f2bf(v);
        float hif = __uint_as_float(((unsigned)hi) << 16);
        unsigned short lo = f2bf(v - hif);
        wph[idx * 8 + j] = hi;
        wpl[idx * 8 + j] = lo;
    }
}

// ---------------------------------------------------------------------------
// Kernel W2: pack w_ih (fwd 0..383 | bwd 384..767) into A-frags, split bf16,
// K = 80 padded to 96 (3 k-steps of 32). Also concat biases.
// ---------------------------------------------------------------------------
__global__ void k_wpack_ih(const float* __restrict__ wf, const float* __restrict__ wb,
                           const float* __restrict__ bf, const float* __restrict__ bbv,
                           unsigned short* __restrict__ wih_h, unsigned short* __restrict__ wih_l,
                           float* __restrict__ biasc) {
    int idx = blockIdx.x * 256 + threadIdx.x;    // over 48*3*64 = 9216
    if (idx < 48 * 3 * 64) {
        int lane = idx & 63;
        int ks   = (idx >> 6) % 3;
        int tau  = idx / (3 * 64);
        int gate = tau * 16 + (lane & 15);
        int kb   = ks * 32 + (lane >> 4) * 8;
        const float* w = (gate < G3) ? (wf + gate * NM) : (wb + (gate - G3) * NM);
#pragma unroll
        for (int j = 0; j < 8; j++) {
            int k = kb + j;
            float v = (k < NM) ? w[k] : 0.f;
            unsigned short hi = f2bf(v);
            float hif = __uint_as_float(((unsigned)hi) << 16);
            unsigned short lo = f2bf(v - hif);
            wih_h[idx * 8 + j] = hi;
            wih_l[idx * 8 + j] = lo;
        }
    }
    if (idx < 768) biasc[idx] = (idx < G3) ? bf[idx] : bbv[idx - G3];
}

// ---------------------------------------------------------------------------
// Kernel A: fused conv1+BN/ReLU+conv2+BN/ReLU — register-resident.
// Block = 256 thr = 2 rows; thread (r, h, g): d in {g, g+64}, m in [40h,40h+40).
// y1 sliding window in regs; conv2 acc c[40] in regs; reduce: 3-level shfl_xor
// butterfly (octets) -> part[2][8][80] (5 KB) -> final 160-thread sum.
// LDS ~6.5 KB, no y1 tile, all melp reads wave-broadcast.
// ---------------------------------------------------------------------------
__global__ __launch_bounds__(256, 4) void k_conv(
    const float* __restrict__ mel, const int* __restrict__ mel_len,
    const float* __restrict__ w1, const float* __restrict__ g1, const float* __restrict__ be1,
    const float* __restrict__ w2, const float* __restrict__ g2, const float* __restrict__ be2,
    float* __restrict__ xout) {
    int b  = blockIdx.y;
    int t0 = blockIdx.x * 2;
    int ml = mel_len[b];
    if (t0 >= ml) return;

    // mp[r][i] = mel[t0+r][i-8] for i in [8,88), else 0.  y1[j] = sum_k w1[k]*mp[j+k]
    __shared__ __align__(16) float mp[2][96];
    __shared__ __align__(16) float part[2][8][80];   // octet partials

    int tid = threadIdx.x;
    int r = tid >> 7, h = (tid >> 6) & 1, g = tid & 63;
    int ms = 40 * h;
    const float inv_sqrt = 0.9999950000374997f;      // 1/sqrt(1+1e-5)

    if (tid < 192) {
        int rr = tid / 96, i = tid - rr * 96;
        float v = 0.f;
        if (i >= 8 && i < 88) v = mel[(b * TT + t0 + rr) * NM + i - 8];
        mp[rr][i] = v;
    }
    __syncthreads();

    float c[40];
#pragma unroll
    for (int m = 0; m < 40; m++) c[m] = 0.f;

    const float* mprow = mp[r];

#pragma unroll 1
    for (int dd = 0; dd < 2; dd++) {
        int d = g + 64 * dd;
        float sc = g1[d] * inv_sqrt;
        float w1r[KK], w2r[KK];
#pragma unroll
        for (int k = 0; k < KK; k++) { w1r[k] = w1[d * KK + k] * sc; w2r[k] = w2[d * KK + k]; }
        float sb = be1[d];

        float mw[16];
        {   // preload mp[ms .. ms+16)
            const float4* p4 = (const float4*)(mprow + ms);
            float4 a = p4[0], bq = p4[1], cq = p4[2], dq = p4[3];
            mw[0]=a.x; mw[1]=a.y; mw[2]=a.z; mw[3]=a.w;
            mw[4]=bq.x; mw[5]=bq.y; mw[6]=bq.z; mw[7]=bq.w;
            mw[8]=cq.x; mw[9]=cq.y; mw[10]=cq.z; mw[11]=cq.w;
            mw[12]=dq.x; mw[13]=dq.y; mw[14]=dq.z; mw[15]=dq.w;
        }
#pragma unroll
        for (int ch = 0; ch < 6; ch++) {
#pragma unroll
            for (int jj = 0; jj < 8; jj++) {
                int off = ch * 8 + jj;           // j = ms + off, static per unroll
                float yv = sb;
#pragma unroll
                for (int k = 0; k < KK; k++) yv = fmaf(w1r[k], mw[jj + k], yv);
                yv = fmaxf(yv, 0.f);
                int j = ms + off;
                if (j < 4 || j >= 84) yv = 0.f;  // conv1 output halo is zero
                // scatter: y1[j] -> c[j-k] for m=j-k in [ms, ms+40)
#pragma unroll
                for (int k = 0; k < KK; k++) {
                    int mo = off - k;            // static
                    if (mo >= 0 && mo < 40) c[mo] = fmaf(w2r[k], yv, c[mo]);
                }
            }
            if (ch < 5) {   // slide window by 8
#pragma unroll
                for (int q = 0; q < 8; q++) mw[q] = mw[q + 8];
                const float4* p4 = (const float4*)(mprow + ms + (ch + 1) * 8 + 8);
                float4 a = p4[0], bq = p4[1];
                mw[8]=a.x; mw[9]=a.y; mw[10]=a.z; mw[11]=a.w;
                mw[12]=bq.x; mw[13]=bq.y; mw[14]=bq.z; mw[15]=bq.w;
            }
        }
    }

    // ---- butterfly reduce over g within octets (lanes of one wave = one (r,h)) ----
#pragma unroll
    for (int m = 0; m < 40; m++) {
        c[m] += __shfl_xor(c[m], 1);
        c[m] += __shfl_xor(c[m], 2);
        c[m] += __shfl_xor(c[m], 4);
    }
    if ((g & 7) == 0) {
        int p = g >> 3;
#pragma unroll
        for (int m = 0; m < 40; m += 4)
            *(float4*)&part[r][p][ms + m] = make_float4(c[m], c[m+1], c[m+2], c[m+3]);
    }
    __syncthreads();

    // ---- final: sum 8 octet partials + BN2/ReLU + store ----
    if (tid < 160) {
        int rr = (tid >= 80) ? 1 : 0;
        int m  = tid - 80 * rr;
        int t  = t0 + rr;
        if (t < ml) {
            float s = 0.f;
#pragma unroll
            for (int p = 0; p < 8; p++) s += part[rr][p][m];
            float v = fmaxf(0.f, fmaf(s, g2[0] * inv_sqrt, be2[0]));
            xout[(b * TT + t) * NM + m] = v;
        }
    }
}

// ---------------------------------------------------------------------------
// Kernel B: projection GEMM via split-bf16 MFMA.
// M=768 gates (A = packed w_ih), K=80 pad 96, N=9600 rows (B = x, staged LDS).
// grid (300 row-tiles of 32, 2 gate-halves of 384), 256 thr (4 waves).
// ---------------------------------------------------------------------------
__global__ __launch_bounds__(256) void k_proj(
    const float* __restrict__ x,
    const unsigned short* __restrict__ wih_h, const unsigned short* __restrict__ wih_l,
    const float* __restrict__ biasc,
    float* __restrict__ xall) {
    __shared__ short8 bhs[2 * 3 * 64];   // B-frags hi: [rg][ks][lane]
    __shared__ short8 bls[2 * 3 * 64];   // B-frags lo

    int tid = threadIdx.x;
    int wave = tid >> 6, lane = tid & 63, quad = lane >> 4;
    int row0 = blockIdx.x * 32;
    int tau0 = blockIdx.y * 24;

    // ---- stage x rows into split-bf16 B-frag layout ----
    for (int i = tid; i < 2 * 3 * 64; i += 256) {
        int rg = i / 192, rem = i - rg * 192;
        int ks = rem >> 6, ln = rem & 63;
        int row = row0 + rg * 16 + (ln & 15);
        int kb = ks * 32 + (ln >> 4) * 8;
        short8 hi8, lo8;
#pragma unroll
        for (int j = 0; j < 8; j++) {
            int k = kb + j;
            float v = (k < NM) ? x[row * NM + k] : 0.f;
            unsigned short hi = f2bf(v);
            float hif = __uint_as_float(((unsigned)hi) << 16);
            hi8[j] = (short)hi;
            lo8[j] = (short)f2bf(v - hif);
        }
        bhs[i] = hi8;
        bls[i] = lo8;
    }
    __syncthreads();

    const short8* wih_h8 = (const short8*)wih_h;
    const short8* wih_l8 = (const short8*)wih_l;

    for (int tt = 0; tt < 6; tt++) {
        int tau = tau0 + wave * 6 + tt;
        short8 Ah[3], Al[3];
#pragma unroll
        for (int ks = 0; ks < 3; ks++) {
            int ia = (tau * 3 + ks) * 64 + lane;
            Ah[ks] = wih_h8[ia];
            Al[ks] = wih_l8[ia];
        }
        f32x4 acc0 = (f32x4){0.f,0.f,0.f,0.f}, acc1 = (f32x4){0.f,0.f,0.f,0.f};
#pragma unroll
        for (int ks = 0; ks < 3; ks++) {
            short8 Bh0 = bhs[ks * 64 + lane],       Bl0 = bls[ks * 64 + lane];
            short8 Bh1 = bhs[192 + ks * 64 + lane], Bl1 = bls[192 + ks * 64 + lane];
            acc0 = __builtin_amdgcn_mfma_f32_16x16x32_bf16(Ah[ks], Bh0, acc0, 0, 0, 0);
            acc0 = __builtin_amdgcn_mfma_f32_16x16x32_bf16(Ah[ks], Bl0, acc0, 0, 0, 0);
            acc0 = __builtin_amdgcn_mfma_f32_16x16x32_bf16(Al[ks], Bh0, acc0, 0, 0, 0);
            acc1 = __builtin_amdgcn_mfma_f32_16x16x32_bf16(Ah[ks], Bh1, acc1, 0, 0, 0);
            acc1 = __builtin_amdgcn_mfma_f32_16x16x32_bf16(Ah[ks], Bl1, acc1, 0, 0, 0);
            acc1 = __builtin_amdgcn_mfma_f32_16x16x32_bf16(Al[ks], Bh1, acc1, 0, 0, 0);
        }
        // C layout: col(N=row)=lane&15, row(M=gate)=quad*4+reg  (m89-verified)
        float4 bias4 = *(const float4*)&biasc[tau * 16 + quad * 4];
        int ga = tau * 16 + quad * 4;
        int rowA = row0 + (lane & 15);
        float4 o0 = make_float4(acc0[0] + bias4.x, acc0[1] + bias4.y,
                                acc0[2] + bias4.z, acc0[3] + bias4.w);
        *(float4*)&xall[rowA * 768 + ga] = o0;
        int rowB = rowA + 16;
        float4 o1 = make_float4(acc1[0] + bias4.x, acc1[1] + bias4.y,
                                acc1[2] + bias4.z, acc1[3] + bias4.w);
        *(float4*)&xall[rowB * 768 + ga] = o1;
    }
}

// ---------------------------------------------------------------------------
// Kernel C: per-segment GRU via MFMA, split-bf16 (unchanged from R2).
// ---------------------------------------------------------------------------
__global__ __launch_bounds__(384) void k_gru(
    const float* __restrict__ xall,
    const unsigned short* __restrict__ wph, const unsigned short* __restrict__ wpl,
    const int* __restrict__ dur_all, const int* __restrict__ starts,
    const int* __restrict__ src_len,
    const float* __restrict__ bhf, const float* __restrict__ bhb,
    float* __restrict__ out) {
    int sblk = blockIdx.x;   // 0..6
    int b    = blockIdx.y;   // 0..7
    int dir  = blockIdx.z;   // 0 fwd, 1 bwd
    int s0 = sblk * 16;

    __shared__ __align__(16) float hs[16][DMC];
    __shared__ __align__(16) unsigned short hbh[4 * 64 * 8];
    __shared__ __align__(16) unsigned short hbl[4 * 64 * 8];
    __shared__ __align__(16) float gbuf[16][388];
    __shared__ int sdur[16], sstart[16];

    int tid  = threadIdx.x;
    int wave = tid >> 6, lane = tid & 63;

    if (tid < 16) {
        int s = s0 + tid;
        sdur[tid]   = (s < SS) ? dur_all[b * SS + s] : 0;
        sstart[tid] = (s < SS) ? starts[b * SS + s]  : 0;
    }
    for (int i = tid; i < 16 * DMC; i += 384) ((float*)hs)[i] = 0.f;
    for (int i = tid; i < 2048; i += 384) { hbh[i] = 0; hbl[i] = 0; }

    short8 Ah[4][4], Al[4][4];
    const short8* wph8 = (const short8*)wph;
    const short8* wpl8 = (const short8*)wpl;
#pragma unroll
    for (int tt = 0; tt < 4; tt++)
#pragma unroll
        for (int k32 = 0; k32 < 4; k32++) {
            int tau = wave * 4 + tt;
            int idx = ((dir * 24 + tau) * 4 + k32) * 64 + lane;
            Ah[tt][k32] = wph8[idx];
            Al[tt][k32] = wpl8[idx];
        }

    const float* bh = dir ? bhb : bhf;
    int xbase = dir * G3;
    int seg_c = lane & 15, quad = lane >> 4;
    __syncthreads();

    for (int i = 0; i < 12; i++) {
        f32x4 acc[4];
#pragma unroll
        for (int tt = 0; tt < 4; tt++) acc[tt] = (f32x4){0.f, 0.f, 0.f, 0.f};
#pragma unroll
        for (int k32 = 0; k32 < 4; k32++) {
            short8 Bh = ((const short8*)hbh)[k32 * 64 + lane];
            short8 Bl = ((const short8*)hbl)[k32 * 64 + lane];
#pragma unroll
            for (int tt = 0; tt < 4; tt++) {
                acc[tt] = __builtin_amdgcn_mfma_f32_16x16x32_bf16(Ah[tt][k32], Bh, acc[tt], 0, 0, 0);
                acc[tt] = __builtin_amdgcn_mfma_f32_16x16x32_bf16(Ah[tt][k32], Bl, acc[tt], 0, 0, 0);
                acc[tt] = __builtin_amdgcn_mfma_f32_16x16x32_bf16(Al[tt][k32], Bh, acc[tt], 0, 0, 0);
            }
        }
#pragma unroll
        for (int tt = 0; tt < 4; tt++) {
            int g = (wave * 4 + tt) * 16 + quad * 4;
            *(f32x4*)&gbuf[seg_c][g] = acc[tt];
        }
        __syncthreads();

        for (int u = tid; u < 16 * DMC; u += 384) {
            int seg = u >> 7, j = u & 127;
            int d = sdur[seg];
            if (i < d) {
                int t = dir ? (sstart[seg] + d - 1 - i) : (sstart[seg] + i);
                const float* xrow = xall + (b * TT + t) * 768 + xbase;
                float xr = xrow[j], xz = xrow[DMC + j], xn = xrow[2 * DMC + j];
                float hr = gbuf[seg][j]           + bh[j];
                float hz = gbuf[seg][DMC + j]     + bh[DMC + j];
                float hn = gbuf[seg][2 * DMC + j] + bh[2 * DMC + j];
                float hold = hs[seg][j];
                float r = sigmoid_(xr + hr);
                float z = sigmoid_(xz + hz);
                float n = tanh_(xn + r * hn);
                float hnew = (1.f - z) * n + z * hold;
                hs[seg][j] = hnew;
                unsigned short hi = f2bf(hnew);
                float hif = __uint_as_float(((unsigned)hi) << 16);
                unsigned short lo = f2bf(hnew - hif);
                int addr = ((j >> 5) * 64 + ((j & 31) >> 3) * 16 + seg) * 8 + (j & 7);
                hbh[addr] = hi;
                hbl[addr] = lo;
                if (i == d - 1) {
                    int s = s0 + seg;
                    float vout = (s < src_len[b]) ? hnew : 0.f;
                    out[(b * SS + s) * (2 * DMC) + dir * DMC + j] = vout;
                }
            }
        }
        __syncthreads();
    }
}

// ---------------------------------------------------------------------------
extern "C" void kernel_launch(void* const* d_in, const int* in_sizes, int n_in,
                              void* d_out, int out_size, void* d_ws, size_t ws_size,
                              hipStream_t stream) {
    const float* mel      = (const float*)d_in[0];
    const int*   durations= (const int*)  d_in[1];
    const int*   mel_len  = (const int*)  d_in[2];
    const int*   src_len  = (const int*)  d_in[3];
    const float* w1       = (const float*)d_in[4];
    const float* g1       = (const float*)d_in[5];
    const float* be1      = (const float*)d_in[6];
    const float* w2       = (const float*)d_in[7];
    const float* g2       = (const float*)d_in[8];
    const float* be2      = (const float*)d_in[9];
    const float* w_ih_f   = (const float*)d_in[10];
    const float* w_hh_f   = (const float*)d_in[11];
    const float* b_ih_f   = (const float*)d_in[12];
    const float* b_hh_f   = (const float*)d_in[13];
    const float* w_ih_b   = (const float*)d_in[14];
    const float* w_hh_b   = (const float*)d_in[15];
    const float* b_ih_b   = (const float*)d_in[16];
    const float* b_hh_b   = (const float*)d_in[17];
    float* out = (float*)d_out;

    // workspace: x | xall | wph | wpl | wih_h | wih_l | biasc | starts
    float* x    = (float*)d_ws;
    float* xall = x + NROW * NM;
    unsigned short* wph   = (unsigned short*)(xall + NROW * 768);
    unsigned short* wpl   = wph + 2 * 24 * 4 * 64 * 8;
    unsigned short* wih_h = wpl + 2 * 24 * 4 * 64 * 8;
    unsigned short* wih_l = wih_h + 48 * 3 * 64 * 8;
    float* biasc = (float*)(wih_l + 48 * 3 * 64 * 8);
    int*   starts= (int*)(biasc + 768);

    k_starts<<<1, dim3(128, 8), 0, stream>>>(durations, starts);
    k_wpack<<<48, 256, 0, stream>>>(w_hh_f, w_hh_b, wph, wpl);
    k_wpack_ih<<<36, 256, 0, stream>>>(w_ih_f, w_ih_b, b_ih_f, b_ih_b, wih_h, wih_l, biasc);
    k_conv<<<dim3(TT / 2, BB), 256, 0, stream>>>(mel, mel_len, w1, g1, be1, w2, g2, be2, x);
    k_proj<<<dim3(NROW / 32, 2), 256, 0, stream>>>(x, wih_h, wih_l, biasc, xall);
    k_gru<<<dim3(7, 8, 2), 384, 0, stream>>>(xall, wph, wpl, durations, starts, src_len,
                                             b_hh_f, b_hh_b, out);
}